// Round 6
// baseline (953.106 us; speedup 1.0000x reference)
//
#include <hip/hip_runtime.h>

#define DEVINL __device__ __forceinline__

constexpr int N_SITES = 500000;
constexpr int C1 = 128;
constexpr int CH = 64;
constexpr int C2 = 128;
constexpr float BN_EPS = 1e-5f;
constexpr int NT32 = N_SITES / 32;   // 15625 tiles of 32 sites (exact)

typedef __attribute__((ext_vector_type(4))) float f32x4;
typedef __attribute__((ext_vector_type(8))) short s16x8;

DEVINL float bf2f(unsigned short s) { return __uint_as_float(((unsigned)s) << 16); }
DEVINL unsigned short f2bf(float f) {
  unsigned u = __float_as_uint(f);
  return (unsigned short)((u + 0x7fffu + ((u >> 16) & 1u)) >> 16);  // RNE
}
DEVINL float silu_f(float x) { return x / (1.0f + __expf(-x)); }

template<bool F32>
DEVINL float rdf(const void* p, long i) {
  if constexpr (F32) return ((const float*)p)[i];
  else return bf2f(((const unsigned short*)p)[i]);
}

DEVINL bool probe_f32(const void* buf) {
  unsigned w = ((const unsigned*)buf)[threadIdx.x & 63];
  unsigned e = (w >> 7) & 0xFFu;
  bool bf_like = (e >= 90u && e <= 134u) || ((w & 0xFFFFu) == 0u);
  return __popcll(__ballot(bf_like)) < 48;
}
DEVINL bool probe_i64(const int* nbr) {
  int v = nbr[2 * (threadIdx.x & 63) + 1];
  return __popcll(__ballot(v == 0)) == 64;
}
template<bool I64>
DEVINL int rd_idx(const int* nbr, long ofs) {
  if constexpr (I64) return nbr[2 * ofs];
  else return nbr[ofs];
}

DEVINL s16x8 as_s16x8(uint4 v) { union { uint4 u; s16x8 s; } c; c.u = v; return c.s; }

DEVINL s16x8 pack8(float a0, float a1, float a2, float a3,
                   float a4, float a5, float a6, float a7) {
  uint4 r;
  r.x = (unsigned)f2bf(a0) | ((unsigned)f2bf(a1) << 16);
  r.y = (unsigned)f2bf(a2) | ((unsigned)f2bf(a3) << 16);
  r.z = (unsigned)f2bf(a4) | ((unsigned)f2bf(a5) << 16);
  r.w = (unsigned)f2bf(a6) | ((unsigned)f2bf(a7) << 16);
  return as_s16x8(r);
}

// Swapped-operand MFMA: D = A*B, A = W^T (m = out-channel), B = data^T
// (n = site).  D: lane (lg*16+lr) holds site lr, channels lg*4+q per m-tile.
DEVINL f32x4 mfma16(s16x8 a, s16x8 b, f32x4 c) {
  return __builtin_amdgcn_mfma_f32_16x16x32_bf16(a, b, c, 0, 0, 0);
}

// Weight fragment packing: element (k, n) of a [K][M] slab -> frag
// (kk = k>>5, mt = n>>4), lane = ((k>>3)&3)*16 + (n&15), j = k&7.

// ---------------------------------------------------------------------------
// K0: pack W2 (scale-folded) into fragment-order bf16 buffer in workspace,
// and zero the 128B sentinel row.
// ---------------------------------------------------------------------------
template<bool F32>
DEVINL void pack_body(const void* W2, const void* g2, const void* v2,
                      unsigned short* __restrict__ w2f)
{
  long idx0 = (long)blockIdx.x * 256 + threadIdx.x;
  for (long idx = idx0; idx < 9 * CH * CH; idx += (long)gridDim.x * 256) {
    int tap = (int)(idx >> 12);
    int k = (int)(idx >> 6) & 63, n = (int)idx & 63;
    float s = rdf<F32>(g2, n) * rsqrtf(rdf<F32>(v2, n) + BN_EPS);
    int frag = (tap * 2 + (k >> 5)) * 4 + (n >> 4);
    int ln = (((k >> 3) & 3) << 4) | (n & 15);
    w2f[(frag * 64 + ln) * 8 + (k & 7)] = f2bf(rdf<F32>(W2, idx) * s);
  }
}

__global__ __launch_bounds__(256) void k_pack(
    const void* W2, const void* g2, const void* v2,
    unsigned short* __restrict__ w2f, unsigned short* __restrict__ zrow)
{
  if (blockIdx.x == 0 && threadIdx.x < 8)
    ((uint4*)zrow)[threadIdx.x] = make_uint4(0u, 0u, 0u, 0u);
  if (probe_f32(W2)) pack_body<true >(W2, g2, v2, w2f);
  else               pack_body<false>(W2, g2, v2, w2f);
}

// ---------------------------------------------------------------------------
// K1: h = silu(bn1(features @ W1)), h bf16 [N][64] ROW-MAJOR (gather target).
// LDS-bounce epilogue -> 16B/lane ascending stores (proven-coalescing size).
// ---------------------------------------------------------------------------
template<bool F32>
DEVINL void cv1_body(const void* feat, const void* W1,
                     const void* g1, const void* b1, const void* m1, const void* v1,
                     unsigned short* __restrict__ h,
                     unsigned short* lw1, float* lsc, float* ltb,
                     unsigned short* sb /* [4 waves][16 rows][72] */)
{
  const int tid = threadIdx.x;
  for (int n = tid; n < CH; n += 256) {
    float s = rdf<F32>(g1, n) * rsqrtf(rdf<F32>(v1, n) + BN_EPS);
    lsc[n] = s;
    ltb[n] = rdf<F32>(b1, n) - rdf<F32>(m1, n) * s;
  }
  __syncthreads();
  for (int idx = tid; idx < C1 * CH; idx += 256) {
    int k = idx >> 6, n = idx & 63;
    int frag = (k >> 5) * 4 + (n >> 4);
    int ln = (((k >> 3) & 3) << 4) | (n & 15);
    lw1[(frag * 64 + ln) * 8 + (k & 7)] = f2bf(rdf<F32>(W1, idx) * lsc[n]);
  }
  __syncthreads();

  const int lane = tid & 63, w = tid >> 6;
  const int lr = lane & 15, lg = lane >> 4;
  const s16x8* lw1s = (const s16x8*)lw1;
  unsigned short* sw = sb + w * (16 * 72);
  s16x8 aw[4][4];
#pragma unroll
  for (int kk = 0; kk < 4; ++kk)
#pragma unroll
    for (int mt = 0; mt < 4; ++mt)
      aw[kk][mt] = lw1s[(kk * 4 + mt) * 64 + lane];

  const int stride = gridDim.x * 4;
  for (int tile = blockIdx.x * 4 + w; tile < NT32; tile += stride) {
    const long base = (long)tile * 32;
    f32x4 acc[2][4];
#pragma unroll
    for (int st = 0; st < 2; ++st)
#pragma unroll
      for (int mt = 0; mt < 4; ++mt) acc[st][mt] = (f32x4)0.0f;

#pragma unroll
    for (int st = 0; st < 2; ++st) {
      const long row = base + st * 16 + lr;
#pragma unroll
      for (int kk = 0; kk < 4; ++kk) {
        s16x8 b;
        if constexpr (F32) {
          const float* fp = (const float*)feat + row * C1 + kk * 32 + lg * 8;
          float4 f0 = ((const float4*)fp)[0];
          float4 f1 = ((const float4*)fp)[1];
          b = pack8(f0.x, f0.y, f0.z, f0.w, f1.x, f1.y, f1.z, f1.w);
        } else {
          b = as_s16x8(*(const uint4*)((const unsigned short*)feat + row * C1 + kk * 32 + lg * 8));
        }
#pragma unroll
        for (int mt = 0; mt < 4; ++mt)
          acc[st][mt] = mfma16(aw[kk][mt], b, acc[st][mt]);
      }
    }
#pragma unroll
    for (int st = 0; st < 2; ++st) {
      __builtin_amdgcn_wave_barrier();
#pragma unroll
      for (int mt = 0; mt < 4; ++mt) {
        int ch4 = mt * 16 + lg * 4;
        f32x4 tb = *(const f32x4*)&ltb[ch4];
        f32x4 v = acc[st][mt];
        ushort4 hv;
        hv.x = f2bf(silu_f(v[0] + tb[0]));
        hv.y = f2bf(silu_f(v[1] + tb[1]));
        hv.z = f2bf(silu_f(v[2] + tb[2]));
        hv.w = f2bf(silu_f(v[3] + tb[3]));
        *(ushort4*)(sw + lr * 72 + ch4) = hv;
      }
      __builtin_amdgcn_wave_barrier();
      uint4 r1 = *(const uint4*)(sw + (lane >> 3) * 72 + (lane & 7) * 8);
      uint4 r2 = *(const uint4*)(sw + (8 + (lane >> 3)) * 72 + (lane & 7) * 8);
      size_t ho = (size_t)(base + st * 16) * CH;
      *(uint4*)(h + ho + lane * 8) = r1;          // 16B/lane ascending
      *(uint4*)(h + ho + 512 + lane * 8) = r2;
      __builtin_amdgcn_wave_barrier();
    }
  }
}

__global__ __launch_bounds__(256, 4) void k_cv1(
    const void* feat, const void* W1,
    const void* g1, const void* b1, const void* m1, const void* v1,
    unsigned short* __restrict__ h)
{
  __shared__ __align__(16) unsigned short lw1[16 * 64 * 8];   // 16 KiB
  __shared__ __align__(16) unsigned short sb[4 * 16 * 72];    // 9.2 KiB
  __shared__ __align__(16) float lsc[CH];
  __shared__ __align__(16) float ltb[CH];
  if (probe_f32(feat)) cv1_body<true >(feat, W1, g1, b1, m1, v1, h, lw1, lsc, ltb, sb);
  else                 cv1_body<false>(feat, W1, g1, b1, m1, v1, h, lw1, lsc, ltb, sb);
}

// ---------------------------------------------------------------------------
// K23 (FUSED cv2+cv3).  W2 taps 0-4 in LDS (40KB, copied from packed buffer);
// taps 5-8 read directly from the packed global buffer (32KB set, L1-resident).
// LDS total 77KB -> 2 blocks/CU -> 16 waves/CU (2x round-5 occupancy).
// ---------------------------------------------------------------------------
#define CV2_ISSUE(slot, tap_) do {                                              \
    const unsigned short* s0_ = (i0[tap_] == N_SITES) ? zrow                     \
                                : h + (size_t)i0[tap_] * CH;                     \
    const unsigned short* s1_ = (i1[tap_] == N_SITES) ? zrow                     \
                                : h + (size_t)i1[tap_] * CH;                     \
    G[slot][0] = as_s16x8(*(const uint4*)(s0_ + lg * 8));                        \
    G[slot][1] = as_s16x8(*(const uint4*)(s0_ + 32 + lg * 8));                   \
    G[slot][2] = as_s16x8(*(const uint4*)(s1_ + lg * 8));                        \
    G[slot][3] = as_s16x8(*(const uint4*)(s1_ + 32 + lg * 8));                   \
  } while (0)

template<bool F32, bool I64>
DEVINL void cv23_body(const unsigned short* __restrict__ h, const int* __restrict__ nbr,
                      const unsigned short* __restrict__ w2f, const void* W3,
                      const void* feat,
                      const void* b2, const void* m2, const void* g2, const void* v2,
                      const void* g3, const void* b3, const void* m3, const void* v3,
                      void* out, const unsigned short* __restrict__ zrow,
                      unsigned short* lw2, unsigned short* swt,
                      float* ltb2, float* lsc3, float* ltb3)
{
  const int tid = threadIdx.x;
  for (int n = tid; n < CH; n += 512) {
    float s = rdf<F32>(g2, n) * rsqrtf(rdf<F32>(v2, n) + BN_EPS);
    ltb2[n] = rdf<F32>(b2, n) - rdf<F32>(m2, n) * s;
  }
  for (int n = tid; n < C2; n += 512) {
    float s = rdf<F32>(g3, n) * rsqrtf(rdf<F32>(v3, n) + BN_EPS);
    lsc3[n] = s;
    ltb3[n] = rdf<F32>(b3, n) - rdf<F32>(m3, n) * s;
  }
  __syncthreads();
  // Copy taps 0-4 fragments from packed buffer: 40960 B straight memcpy.
  for (int i = tid; i < 2560; i += 512)
    ((uint4*)lw2)[i] = ((const uint4*)w2f)[i];

  const int lane = tid & 63, w = tid >> 6;   // w in [0,8)
  const int lr = lane & 15, lg = lane >> 4;

  // W3^T A-fragments in registers (scale-folded): one-time cost.
  s16x8 aw3[2][8];
#pragma unroll
  for (int kk = 0; kk < 2; ++kk)
#pragma unroll
    for (int mm = 0; mm < 8; ++mm) {
      float sc = lsc3[mm * 16 + lr];
      float e[8];
#pragma unroll
      for (int j = 0; j < 8; ++j)
        e[j] = rdf<F32>(W3, (long)(kk * 32 + lg * 8 + j) * C2 + mm * 16 + lr) * sc;
      aw3[kk][mm] = pack8(e[0], e[1], e[2], e[3], e[4], e[5], e[6], e[7]);
    }
  __syncthreads();

  const s16x8* lw2s = (const s16x8*)lw2;
  const s16x8* w2fs = (const s16x8*)w2f;
  unsigned short* sw = swt + w * 2176;   // per-wave scratch (16x136 ushorts)

  const int stride = gridDim.x * 8;
  for (int tile = blockIdx.x * 8 + w; tile < NT32; tile += stride) {
    const long base = (long)tile * 32;
    int i0[9], i1[9];
#pragma unroll
    for (int tap = 0; tap < 9; ++tap) {
      i0[tap] = rd_idx<I64>(nbr, (long)tap * N_SITES + base + lr);
      i1[tap] = rd_idx<I64>(nbr, (long)tap * N_SITES + base + 16 + lr);
    }
    f32x4 acc[2][4];
#pragma unroll
    for (int st = 0; st < 2; ++st)
#pragma unroll
      for (int mt = 0; mt < 4; ++mt) acc[st][mt] = (f32x4)0.0f;

    s16x8 G[3][4];
    CV2_ISSUE(0, 0); CV2_ISSUE(1, 1); CV2_ISSUE(2, 2);
#pragma unroll
    for (int tap = 0; tap < 9; ++tap) {
      const int slot = tap % 3;
#pragma unroll
      for (int mt = 0; mt < 4; ++mt) {
        s16x8 a0, a1;
        if (tap < 5) {   // compile-time after unroll
          a0 = lw2s[((tap * 2 + 0) * 4 + mt) * 64 + lane];
          a1 = lw2s[((tap * 2 + 1) * 4 + mt) * 64 + lane];
        } else {
          a0 = w2fs[((tap * 2 + 0) * 4 + mt) * 64 + lane];
          a1 = w2fs[((tap * 2 + 1) * 4 + mt) * 64 + lane];
        }
        acc[0][mt] = mfma16(a0, G[slot][0], acc[0][mt]);
        acc[0][mt] = mfma16(a1, G[slot][1], acc[0][mt]);
        acc[1][mt] = mfma16(a0, G[slot][2], acc[1][mt]);
        acc[1][mt] = mfma16(a1, G[slot][3], acc[1][mt]);
      }
      if (tap + 3 < 9) CV2_ISSUE(slot, tap + 3);
    }

    // ---- cv3, per st half-tile (scratch reused) ----
#pragma unroll
    for (int st = 0; st < 2; ++st) {
      __builtin_amdgcn_wave_barrier();
#pragma unroll
      for (int mt = 0; mt < 4; ++mt) {
        int ch4 = mt * 16 + lg * 4;
        f32x4 tbv = *(const f32x4*)&ltb2[ch4];
        f32x4 v = acc[st][mt];
        ushort4 tv;
        tv.x = f2bf(silu_f(v[0] + tbv[0]));
        tv.y = f2bf(silu_f(v[1] + tbv[1]));
        tv.z = f2bf(silu_f(v[2] + tbv[2]));
        tv.w = f2bf(silu_f(v[3] + tbv[3]));
        *(ushort4*)(sw + lr * 72 + ch4) = tv;
      }
      __builtin_amdgcn_wave_barrier();
      s16x8 bfr0 = *(const s16x8*)(sw + lr * 72 + lg * 8);
      s16x8 bfr1 = *(const s16x8*)(sw + lr * 72 + 32 + lg * 8);
      f32x4 acc3[8];
#pragma unroll
      for (int mm = 0; mm < 8; ++mm) acc3[mm] = (f32x4)0.0f;
#pragma unroll
      for (int mm = 0; mm < 8; ++mm) acc3[mm] = mfma16(aw3[0][mm], bfr0, acc3[mm]);
#pragma unroll
      for (int mm = 0; mm < 8; ++mm) acc3[mm] = mfma16(aw3[1][mm], bfr1, acc3[mm]);

      const size_t site = (size_t)(base + st * 16 + lr);
      if constexpr (F32) {
#pragma unroll
        for (int mm = 0; mm < 8; ++mm) {
          int ch4 = mm * 16 + lg * 4;
          f32x4 tbv = *(const f32x4*)&ltb3[ch4];
          float4 fv = *(const float4*)((const float*)feat + site * C1 + ch4);
          float4 ov;
          ov.x = silu_f(acc3[mm][0] + tbv[0] + fv.x);
          ov.y = silu_f(acc3[mm][1] + tbv[1] + fv.y);
          ov.z = silu_f(acc3[mm][2] + tbv[2] + fv.z);
          ov.w = silu_f(acc3[mm][3] + tbv[3] + fv.w);
          *(float4*)((float*)out + site * C2 + ch4) = ov;   // 16B/lane
        }
      } else {
        __builtin_amdgcn_wave_barrier();
#pragma unroll
        for (int mm = 0; mm < 8; ++mm) {
          int ch4 = mm * 16 + lg * 4;
          f32x4 tbv = *(const f32x4*)&ltb3[ch4];
          ushort4 ov;
          ov.x = f2bf(acc3[mm][0] + tbv[0]);
          ov.y = f2bf(acc3[mm][1] + tbv[1]);
          ov.z = f2bf(acc3[mm][2] + tbv[2]);
          ov.w = f2bf(acc3[mm][3] + tbv[3]);
          *(ushort4*)(sw + lr * 136 + ch4) = ov;
        }
        __builtin_amdgcn_wave_barrier();
#pragma unroll
        for (int p = 0; p < 4; ++p) {
          int r = p * 4 + (lane >> 4);
          int c8 = (lane & 15) * 8;
          const unsigned short* sp = sw + r * 136 + c8;
          size_t srow = (size_t)(base + st * 16 + r) * C2 + c8;
          const unsigned short* fp = (const unsigned short*)feat + srow;
          unsigned short* op = (unsigned short*)out + srow;
          ushort4 o0 = *(const ushort4*)sp, o1 = *(const ushort4*)(sp + 4);
          ushort4 f0 = *(const ushort4*)fp, f1 = *(const ushort4*)(fp + 4);
          ushort4 w0, w1;
          w0.x = f2bf(silu_f(bf2f(o0.x) + bf2f(f0.x)));
          w0.y = f2bf(silu_f(bf2f(o0.y) + bf2f(f0.y)));
          w0.z = f2bf(silu_f(bf2f(o0.z) + bf2f(f0.z)));
          w0.w = f2bf(silu_f(bf2f(o0.w) + bf2f(f0.w)));
          w1.x = f2bf(silu_f(bf2f(o1.x) + bf2f(f1.x)));
          w1.y = f2bf(silu_f(bf2f(o1.y) + bf2f(f1.y)));
          w1.z = f2bf(silu_f(bf2f(o1.z) + bf2f(f1.z)));
          w1.w = f2bf(silu_f(bf2f(o1.w) + bf2f(f1.w)));
          *(ushort4*)op = w0;
          *(ushort4*)(op + 4) = w1;
        }
        __builtin_amdgcn_wave_barrier();
      }
    }
  }
}

__global__ __launch_bounds__(512, 4) void k_cv23(
    const unsigned short* __restrict__ h, const int* __restrict__ nbr,
    const unsigned short* __restrict__ w2f, const void* W3, const void* feat,
    const void* b2, const void* m2, const void* g2, const void* v2,
    const void* g3, const void* b3, const void* m3, const void* v3,
    void* out, const unsigned short* __restrict__ zrow)
{
  __shared__ __align__(16) unsigned short lw2[5 * 8 * 64 * 8];  // 40960 B
  __shared__ __align__(16) unsigned short swt[8 * 2176];        // 34816 B
  __shared__ __align__(16) float ltb2[CH];
  __shared__ __align__(16) float lsc3[C2], ltb3[C2];
  bool f32 = probe_f32(feat);
  bool i64 = probe_i64(nbr);
  if (f32) { if (i64) cv23_body<true , true >(h, nbr, w2f, W3, feat, b2, m2, g2, v2, g3, b3, m3, v3, out, zrow, lw2, swt, ltb2, lsc3, ltb3);
             else     cv23_body<true , false>(h, nbr, w2f, W3, feat, b2, m2, g2, v2, g3, b3, m3, v3, out, zrow, lw2, swt, ltb2, lsc3, ltb3); }
  else     { if (i64) cv23_body<false, true >(h, nbr, w2f, W3, feat, b2, m2, g2, v2, g3, b3, m3, v3, out, zrow, lw2, swt, ltb2, lsc3, ltb3);
             else     cv23_body<false, false>(h, nbr, w2f, W3, feat, b2, m2, g2, v2, g3, b3, m3, v3, out, zrow, lw2, swt, ltb2, lsc3, ltb3); }
}

// ---------------------------------------------------------------------------
extern "C" void kernel_launch(void* const* d_in, const int* in_sizes, int n_in,
                              void* d_out, int out_size, void* d_ws, size_t ws_size,
                              hipStream_t stream)
{
  (void)out_size; (void)ws_size;
  // dict order: feat nbr W1 W2 W3 g1 b1 m1 v1 g2 b2 m2 v2 g3 b3 m3 v3
  int mp[17];
  for (int i = 0; i < 17; ++i) mp[i] = i;
  if (n_in == 17 && in_sizes[0] != 64000000 &&
      in_sizes[6] == 64000000 && in_sizes[13] == 4500000) {
    const int amap[17] = {6, 13, 0, 1, 2, 7, 3, 10, 14, 8, 4, 11, 15, 9, 5, 12, 16};
    for (int i = 0; i < 17; ++i) mp[i] = amap[i];
  }
  const void* feat = d_in[mp[0]];
  const int*  nbr  = (const int*)d_in[mp[1]];
  const void* W1 = d_in[mp[2]];
  const void* W2 = d_in[mp[3]];
  const void* W3 = d_in[mp[4]];
  const void* g1 = d_in[mp[5]],  *b1 = d_in[mp[6]],  *m1 = d_in[mp[7]],  *v1 = d_in[mp[8]];
  const void* g2 = d_in[mp[9]],  *b2 = d_in[mp[10]], *m2 = d_in[mp[11]], *v2 = d_in[mp[12]];
  const void* g3 = d_in[mp[13]], *b3 = d_in[mp[14]], *m3 = d_in[mp[15]], *v3 = d_in[mp[16]];

  // workspace layout:
  //   h    @ 0          : N*64 bf16 row-major (64,000,000 B)
  //   zrow @ 64,000,000 : 128 B zero sentinel row (256 B slot)
  //   w2f  @ 64,000,256 : packed W2 fragments, bf16, 73,728 B
  unsigned short* h    = (unsigned short*)d_ws;
  unsigned short* zrow = (unsigned short*)((char*)d_ws + 64000000);
  unsigned short* w2f  = (unsigned short*)((char*)d_ws + 64000256);

  k_pack<<<64, 256, 0, stream>>>(W2, g2, v2, w2f, zrow);
  k_cv1<<<2048, 256, 0, stream>>>(feat, W1, g1, b1, m1, v1, h);
  k_cv23<<<512, 512, 0, stream>>>(h, nbr, w2f, W3, feat,
                                  b2, m2, g2, v2, g3, b3, m3, v3,
                                  (void*)d_out, zrow);
}